// Round 10
// baseline (130.309 us; speedup 1.0000x reference)
//
#include <hip/hip_runtime.h>
#include <hip/hip_bf16.h>
#include <stdint.h>

// BiLevelRoutingAttention (spiking LIF), T=4 B=2 L=8x32x32 C=256, fp32 I/O.
#define NT 4
#define NB 2
#define NW 32   // windows = 2*4*4
#define NS 256  // tokens/window = 4*8*8
#define NC 256
#define NH 8
#define ND 32
#define NK 4    // topk

typedef unsigned int u32;
typedef unsigned long long u64;
typedef unsigned short u16;
typedef __attribute__((ext_vector_type(8))) short bf16x8;
typedef __attribute__((ext_vector_type(4))) float f32x4;

// natural token index: tok = (t*NB+b)*8192 + Lt*1024 + Lh*32 + Lw
__device__ __forceinline__ int wofs(int w) {
  return (w >> 4) * 4096 + ((w >> 2) & 3) * 256 + (w & 3) * 8;
}
__device__ __forceinline__ int sofs(int s) {
  return ((s >> 6) << 10) + (((s >> 3) & 7) << 5) + (s & 7);
}
__device__ __forceinline__ size_t x_off(int t, int b, int w, int s, int c) {
  return ((size_t)((t * NB + b) * 8192 + wofs(w) + sofs(s))) * NC + c;
}

// fp32 -> bf16 round-to-nearest-even
__device__ __forceinline__ u32 f2bf(float f) {
  union { float f; u32 i; } u; u.f = f;
  return (u.i + 0x7FFFu + ((u.i >> 16) & 1u)) >> 16;
}

// async global(16B/lane) -> LDS (wave-uniform base + lane*16)
__device__ __forceinline__ void gload16(const u16* g, u16* l) {
  __builtin_amdgcn_global_load_lds(
      (const __attribute__((address_space(1))) void*)g,
      (__attribute__((address_space(3))) void*)l, 16, 0, 0);
}

// K1: prep. Blocks 0..511: x fp32 -> xw bf16 (natural order) + region atomics.
// Blocks 512..515: w_qkv -> bt (transposed bf16).
__global__ __launch_bounds__(256) void k_prep(const float* __restrict__ x,
                                              const float* __restrict__ w_qkv,
                                              u16* __restrict__ xw,
                                              u16* __restrict__ bt,
                                              float* __restrict__ region) {
  int blk = blockIdx.x, tid = threadIdx.x;
  if (blk >= 512) {
    for (int i = (blk - 512) * 256 + tid; i < 256 * 768; i += 1024) {
      int k = i / 768, n = i % 768;
      bt[(size_t)n * 256 + k] = (u16)f2bf(w_qkv[i]);
    }
    return;
  }
  __shared__ float sums[4][4][NC];  // [ww][g][c] 16 KB
  int g = tid >> 6, c4 = tid & 63;
  size_t base = (size_t)blk * 128;  // 128 tokens/block
  float4 s[4];
#pragma unroll
  for (int ww = 0; ww < 4; ++ww) s[ww] = make_float4(0.f, 0.f, 0.f, 0.f);
#pragma unroll
  for (int p = 0; p < 32; ++p) {
    int row = p * 4 + g;
    float4 v = *reinterpret_cast<const float4*>(&x[(base + row) * NC + c4 * 4]);
    uint2 bf;
    bf.x = f2bf(v.x) | (f2bf(v.y) << 16);
    bf.y = f2bf(v.z) | (f2bf(v.w) << 16);
    *reinterpret_cast<uint2*>(&xw[(base + row) * NC + c4 * 4]) = bf;
    int ww = (p & 7) >> 1;  // = (row&31)>>3
    s[ww].x += v.x; s[ww].y += v.y; s[ww].z += v.z; s[ww].w += v.w;
  }
#pragma unroll
  for (int ww = 0; ww < 4; ++ww)
    *reinterpret_cast<float4*>(&sums[ww][g][c4 * 4]) = s[ww];
  __syncthreads();
  // block = tb*64 + Lt*8 + hp ; wh = hp>>1, wt = Lt>>2 (4 Lh rows stay in one wh)
  int b = (blk >> 6) & 1;
  int wt = ((blk >> 3) & 7) >> 2, wh = (blk & 7) >> 1;
  int v0 = wt * 16 + wh * 4;
  int c = tid;
#pragma unroll
  for (int ww = 0; ww < 4; ++ww) {
    float tot = (sums[ww][0][c] + sums[ww][1][c] + sums[ww][2][c] + sums[ww][3][c]) *
                (1.0f / 1024.0f);
    atomicAdd(&region[((size_t)b * NW + v0 + ww) * NC + c], tot);
  }
}

// K2: scores + top-4 (ties -> lower index, matching jax.lax.top_k)
__global__ __launch_bounds__(256) void k_scores(const float* __restrict__ region,
                                                int* __restrict__ idx) {
  __shared__ float rs[NW][NC];  // 32 KB
  __shared__ float scval[NW];
  int blk = blockIdx.x;  // 64 = b*32 + w
  int b = blk >> 5, w = blk & 31;
  int tid = threadIdx.x;
  for (int i = tid; i < NW * NC; i += 256)
    rs[i >> 8][i & 255] = region[(size_t)b * NW * NC + i];
  __syncthreads();
  int v = tid >> 3, l8 = tid & 7;
  float sum = 0.f;
  const float* a = rs[w];
  const float* bb = rs[v];
#pragma unroll
  for (int j = 0; j < 32; ++j) sum += a[l8 * 32 + j] * bb[l8 * 32 + j];
  sum += __shfl_xor(sum, 1);
  sum += __shfl_xor(sum, 2);
  sum += __shfl_xor(sum, 4);
  if (l8 == 0) scval[v] = sum * 0.17677669529663687f;  // 32^-0.5
  __syncthreads();
  if (tid == 0) {
    float sc[NW];
#pragma unroll
    for (int j = 0; j < NW; ++j) sc[j] = scval[j];
    for (int kk = 0; kk < NK; ++kk) {
      float best = -__builtin_inff(); int bi = 0;
      for (int j = 0; j < NW; ++j)
        if (sc[j] > best) { best = sc[j]; bi = j; }
      idx[(b * NW + w) * NK + kk] = bi;
      sc[bi] = -__builtin_inff();
    }
  }
}

// K3: MFMA GEMM (natural token order), global_load_lds staging, XOR-swizzled LDS
// (linear dest + pre-swizzled global source + swizzled ds_read — rule both-sides).
// qkv[65536][768] = xw @ w_qkv + b_qkv; spike bits (>=2.0) -> q/k/v bitmasks via
// __ballot; per-window flags. 128x128 tile, BK=32 dbuf, 4 waves x 4x4 16x16x32.
__global__ __launch_bounds__(256) void k_gemm(const u16* __restrict__ xw,
                                              const u16* __restrict__ bt,
                                              const float* __restrict__ b_qkv,
                                              u32* __restrict__ qb, u32* __restrict__ kb,
                                              u32* __restrict__ vb,
                                              u32* __restrict__ winflag) {
  __shared__ __align__(16) u16 As[2][128 * 32];
  __shared__ __align__(16) u16 Bs[2][128 * 32];
  __shared__ u32 wfl;

  const int tid = threadIdx.x;
  // XCD-chunked m-major: 6 consecutive v share one m-tile (A panel L2 reuse).
  const int v = (blockIdx.x & 7) * 384 + (blockIdx.x >> 3);
  const int mt = v / 6, nt = v % 6;
  const int m0 = mt * 128, n0 = nt * 128;
  const int wave = tid >> 6, lane = tid & 63;
  const int wr = wave >> 1, wc = wave & 1;

  if (tid == 0) wfl = 0;

  const f32x4 vz = {0.f, 0.f, 0.f, 0.f};
  f32x4 acc[4][4];
#pragma unroll
  for (int m = 0; m < 4; ++m)
#pragma unroll
    for (int n = 0; n < 4; ++n) acc[m][n] = vz;

  auto stage = [&](int buf, int ks) {
    const int k0 = ks * 32;
#pragma unroll
    for (int p = 0; p < 2; ++p) {
      int idx2 = p * 256 + wave * 64 + lane;
      int row = idx2 >> 2, sl = idx2 & 3;
      int ssl = sl ^ ((row >> 1) & 3);          // pre-swizzled source slot
      int lbase = (p * 256 + wave * 64) * 8;    // linear LDS dest (HW adds lane*16B)
      gload16(&xw[(size_t)(m0 + row) * 256 + k0 + ssl * 8], &As[buf][lbase]);
      gload16(&bt[(size_t)(n0 + row) * 256 + k0 + ssl * 8], &Bs[buf][lbase]);
    }
  };

  stage(0, 0);
  __syncthreads();
#pragma unroll
  for (int ks = 0; ks < 8; ++ks) {
    const int buf = ks & 1;
    if (ks < 7) stage(buf ^ 1, ks + 1);
    bf16x8 afr[4], bfr[4];
#pragma unroll
    for (int m = 0; m < 4; ++m) {
      int r = wr * 64 + m * 16 + (lane & 15);
      int phys = (lane >> 4) ^ ((r >> 1) & 3);  // swizzled read
      afr[m] = *reinterpret_cast<const bf16x8*>(&As[buf][r * 32 + phys * 8]);
    }
#pragma unroll
    for (int n = 0; n < 4; ++n) {
      int r = wc * 64 + n * 16 + (lane & 15);
      int phys = (lane >> 4) ^ ((r >> 1) & 3);
      bfr[n] = *reinterpret_cast<const bf16x8*>(&Bs[buf][r * 32 + phys * 8]);
    }
#pragma unroll
    for (int m = 0; m < 4; ++m)
#pragma unroll
      for (int n = 0; n < 4; ++n)
        acc[m][n] = __builtin_amdgcn_mfma_f32_16x16x32_bf16(afr[m], bfr[n], acc[m][n], 0, 0, 0);
    __syncthreads();
  }

  // epilogue: threshold via wave ballot (C/D layout: bit l = row (l>>4)*4+r, col l&15)
  float bias[4];
#pragma unroll
  for (int n = 0; n < 4; ++n) bias[n] = b_qkv[n0 + wc * 64 + n * 16 + (lane & 15)];
  u32* dst = (nt < 2) ? qb : (nt < 4) ? kb : vb;
  const int h0 = (nt * 4) & 7;
  const int g = lane >> 4;
  u32 wfl_loc = 0;
#pragma unroll
  for (int m = 0; m < 4; ++m)
#pragma unroll
    for (int r = 0; r < 4; ++r) {
      u32 words[2];
#pragma unroll
      for (int np = 0; np < 2; ++np) {
        u64 b0 = __ballot(acc[m][2 * np][r] + bias[2 * np] >= 2.0f);
        u64 b1 = __ballot(acc[m][2 * np + 1][r] + bias[2 * np + 1] >= 2.0f);
        words[np] = (u32)((b0 >> (g * 16)) & 0xFFFFu) |
                    ((u32)((b1 >> (g * 16)) & 0xFFFFu) << 16);
      }
      if ((lane & 15) < 2) {
        int np = lane & 1;
        int row = wr * 64 + m * 16 + g * 4 + r;
        u32 wv = words[np];
        dst[(size_t)(m0 + row) * NH + h0 + wc * 2 + np] = wv;
        if (wv) wfl_loc |= 1u << ((row & 31) >> 3);  // ww class
      }
    }
  if (wfl_loc) atomicOr(&wfl, wfl_loc);
  __syncthreads();
  if (tid == 0 && wfl) {
    int t = mt >> 7, b = (mt >> 6) & 1, Lt = (mt >> 3) & 7, hh = mt & 7;
    int w0 = (Lt >> 2) * 16 + (hh >> 1) * 4;
    u32 bit = (nt < 2) ? 1u : (nt < 4) ? 2u : 4u;
    for (int ww = 0; ww < 4; ++ww)
      if (wfl & (1u << ww))
        atomicOr(&winflag[(t * NB + b) * NW + w0 + ww], bit);
  }
}

// K4: attention + proj + window reverse; s-chunked 4x; fast path via window flags.
__global__ __launch_bounds__(256) void k_attn(const u32* __restrict__ qb,
                                              const u32* __restrict__ kb,
                                              const u32* __restrict__ vb,
                                              const int* __restrict__ idx,
                                              const u32* __restrict__ winflag,
                                              const float* __restrict__ w_proj,
                                              const float* __restrict__ b_proj,
                                              float* __restrict__ out) {
  __shared__ u32 qs[64 * NH];
  __shared__ unsigned short kvc[NH * ND * ND];
  __shared__ u32 ksum[NH * ND];
  __shared__ float attnrow[NC];

  int blk = blockIdx.x;  // 1024 = wid*4 + sc
  int wid = blk >> 2, sc = blk & 3;
  int t = wid >> 6, b = (wid >> 5) & 1, w = wid & 31;
  int s0 = sc * 64;
  int tid = threadIdx.x;

  u32 fs = winflag[(t * NB + b) * NW + w];
  int wj[NK];
  u32 fk = 0, fv = 0;
#pragma unroll
  for (int j = 0; j < NK; ++j) {
    wj[j] = idx[(b * NW + w) * NK + j];
    u32 f = winflag[(t * NB + b) * NW + wj[j]];
    fk |= f & 2u; fv |= f & 4u;
  }
  bool skip = !(fs & 1u) || !fk || !fv;

  if (skip) {
    float bp = b_proj[tid];
    for (int s = s0; s < s0 + 64; ++s) out[x_off(t, b, w, s, tid)] = bp;
    return;
  }

  // ---- exact integer slow path (only if spikes exist) ----
  int tb = (t * NB + b) * 8192;
  size_t gb[NK];
#pragma unroll
  for (int j = 0; j < NK; ++j) gb[j] = (size_t)(tb + wofs(wj[j])) * NH;
  size_t qbase = (size_t)(tb + wofs(w)) * NH;
  for (int i = tid; i < 64 * NH; i += 256)
    qs[i] = qb[qbase + (size_t)sofs(s0 + (i >> 3)) * NH + (i & 7)];
  {
    int h = tid >> 5, d = tid & 31;
    u32 cnt = 0;
    for (int n = 0; n < NK * NS; ++n)
      cnt += (kb[gb[n >> 8] + (size_t)sofs(n & 255) * NH + h] >> d) & 1u;
    ksum[tid] = cnt;
  }
  for (int p = tid; p < NH * ND * ND; p += 256) {
    int h = p >> 10, d = (p >> 5) & 31, e = p & 31;
    u32 cnt = 0;
    for (int n = 0; n < NK * NS; ++n) {
      size_t a = gb[n >> 8] + (size_t)sofs(n & 255) * NH + h;
      cnt += ((kb[a] >> d) & (vb[a] >> e)) & 1u;
    }
    kvc[p] = (unsigned short)cnt;
  }
  __syncthreads();
  int h = tid >> 5, e = tid & 31;
  float bpv = b_proj[tid];
  for (int sl = 0; sl < 64; ++sl) {
    u32 qw = qs[sl * NH + h];
    float num = 0.f, den = 0.f;
    for (int d = 0; d < ND; ++d) {
      if ((qw >> d) & 1u) {
        den += (float)ksum[h * ND + d];
        num += (float)kvc[h * ND * ND + d * ND + e];
      }
    }
    attnrow[tid] = num / (den + 1e-6f);
    __syncthreads();
    float acc = bpv;
    for (int c = 0; c < NC; ++c) acc += attnrow[c] * w_proj[c * NC + tid];
    out[x_off(t, b, w, s0 + sl, tid)] = acc;
    __syncthreads();
  }
}

extern "C" void kernel_launch(void* const* d_in, const int* in_sizes, int n_in,
                              void* d_out, int out_size, void* d_ws, size_t ws_size,
                              hipStream_t stream) {
  const float* x      = (const float*)d_in[0];
  const float* w_qkv  = (const float*)d_in[1];
  const float* b_qkv  = (const float*)d_in[2];
  const float* w_proj = (const float*)d_in[3];
  const float* b_proj = (const float*)d_in[4];
  float* out = (float*)d_out;

  char* ws = (char*)d_ws;
  int* idx       = (int*)(ws + 0x200000);         // 1 KB
  u16* bt        = (u16*)(ws + 0x201000);         // 384 KB bf16 [768][256]
  u32* winflag   = (u32*)(ws + 0x270000);         // 1 KB (t,b,w): bit0 q, bit1 k, bit2 v
  float* region  = (float*)(ws + 0x271000);       // 64 KB [b][v][c]
  u32* qb        = (u32*)(ws + 0x300000);         // 2 MB each, natural token order
  u32* kb        = qb + (size_t)NT * NB * NW * NS * NH;
  u32* vb        = kb + (size_t)NT * NB * NW * NS * NH;
  u16* xw        = (u16*)(ws + 0x900000);         // 32 MB bf16 [65536][256]

  hipMemsetAsync(ws + 0x270000, 0, 0x11000, stream);  // winflag + region
  k_prep<<<516, 256, 0, stream>>>(x, w_qkv, xw, bt, region);
  k_scores<<<NB * NW, 256, 0, stream>>>(region, idx);
  k_gemm<<<3072, 256, 0, stream>>>(xw, bt, b_qkv, qb, kb, vb, winflag);
  k_attn<<<NT * NB * NW * 4, 256, 0, stream>>>(qb, kb, vb, idx, winflag, w_proj, b_proj, out);
}

// Round 11
// 88.066 us; speedup vs baseline: 1.4797x; 1.4797x over previous
//
#include <hip/hip_runtime.h>
#include <hip/hip_bf16.h>
#include <stdint.h>

// BiLevelRoutingAttention (spiking LIF), T=4 B=2 L=8x32x32 C=256, fp32 I/O.
#define NT 4
#define NB 2
#define NW 32   // windows = 2*4*4
#define NS 256  // tokens/window = 4*8*8
#define NC 256
#define NH 8
#define ND 32
#define NK 4    // topk

typedef unsigned int u32;
typedef unsigned long long u64;
typedef unsigned short u16;
typedef __attribute__((ext_vector_type(8))) short bf16x8;
typedef __attribute__((ext_vector_type(4))) float f32x4;

// natural token index: tok = (t*NB+b)*8192 + Lt*1024 + Lh*32 + Lw
__device__ __forceinline__ int wofs(int w) {
  return (w >> 4) * 4096 + ((w >> 2) & 3) * 256 + (w & 3) * 8;
}
__device__ __forceinline__ int sofs(int s) {
  return ((s >> 6) << 10) + (((s >> 3) & 7) << 5) + (s & 7);
}
__device__ __forceinline__ size_t x_off(int t, int b, int w, int s, int c) {
  return ((size_t)((t * NB + b) * 8192 + wofs(w) + sofs(s))) * NC + c;
}

// fp32 -> bf16 round-to-nearest-even
__device__ __forceinline__ u32 f2bf(float f) {
  union { float f; u32 i; } u; u.f = f;
  return (u.i + 0x7FFFu + ((u.i >> 16) & 1u)) >> 16;
}

// async global(16B/lane) -> LDS (wave-uniform base + lane*16)
__device__ __forceinline__ void gload16(const u16* g, u16* l) {
  __builtin_amdgcn_global_load_lds(
      (const __attribute__((address_space(1))) void*)g,
      (__attribute__((address_space(3))) void*)l, 16, 0, 0);
}

// K1: prep. Blocks 0..511: x fp32 -> xw bf16 (natural order) + region atomics.
// Blocks 512..607: w_qkv -> bt (transposed bf16), 1 (n,kchunk) pair per thread,
// coalesced 16B writes, L2-cached scattered reads.
__global__ __launch_bounds__(256) void k_prep(const float* __restrict__ x,
                                              const float* __restrict__ w_qkv,
                                              u16* __restrict__ xw,
                                              u16* __restrict__ bt,
                                              float* __restrict__ region) {
  int blk = blockIdx.x, tid = threadIdx.x;
  if (blk >= 512) {
    int n = (blk - 512) * 8 + (tid >> 5);  // 0..767
    int kc = tid & 31;                     // k-chunk of 8
    u16 vals[8];
#pragma unroll
    for (int j = 0; j < 8; ++j)
      vals[j] = (u16)f2bf(w_qkv[(size_t)(kc * 8 + j) * 768 + n]);
    *reinterpret_cast<uint4*>(&bt[(size_t)n * 256 + kc * 8]) =
        *reinterpret_cast<const uint4*>(vals);
    return;
  }
  __shared__ float sums[4][4][NC];  // [ww][g][c] 16 KB
  int g = tid >> 6, c4 = tid & 63;
  size_t base = (size_t)blk * 128;  // 128 tokens/block
  float4 s[4];
#pragma unroll
  for (int ww = 0; ww < 4; ++ww) s[ww] = make_float4(0.f, 0.f, 0.f, 0.f);
#pragma unroll
  for (int p = 0; p < 32; ++p) {
    int row = p * 4 + g;
    float4 v = *reinterpret_cast<const float4*>(&x[(base + row) * NC + c4 * 4]);
    uint2 bf;
    bf.x = f2bf(v.x) | (f2bf(v.y) << 16);
    bf.y = f2bf(v.z) | (f2bf(v.w) << 16);
    *reinterpret_cast<uint2*>(&xw[(base + row) * NC + c4 * 4]) = bf;
    int ww = (p & 7) >> 1;  // = (row&31)>>3
    s[ww].x += v.x; s[ww].y += v.y; s[ww].z += v.z; s[ww].w += v.w;
  }
#pragma unroll
  for (int ww = 0; ww < 4; ++ww)
    *reinterpret_cast<float4*>(&sums[ww][g][c4 * 4]) = s[ww];
  __syncthreads();
  // blk = tb*64 + Lt*8 + hp ; wh = hp>>1, wt = Lt>>2
  int b = (blk >> 6) & 1;
  int wt = ((blk >> 3) & 7) >> 2, wh = (blk & 7) >> 1;
  int v0 = wt * 16 + wh * 4;
  int c = tid;
#pragma unroll
  for (int ww = 0; ww < 4; ++ww) {
    float tot = (sums[ww][0][c] + sums[ww][1][c] + sums[ww][2][c] + sums[ww][3][c]) *
                (1.0f / 1024.0f);
    atomicAdd(&region[((size_t)b * NW + v0 + ww) * NC + c], tot);
  }
}

// K2: scores + top-4 (ties -> lower index, matching jax.lax.top_k)
__global__ __launch_bounds__(256) void k_scores(const float* __restrict__ region,
                                                int* __restrict__ idx) {
  __shared__ float rs[NW][NC];  // 32 KB
  __shared__ float scval[NW];
  int blk = blockIdx.x;  // 64 = b*32 + w
  int b = blk >> 5, w = blk & 31;
  int tid = threadIdx.x;
  for (int i = tid; i < NW * NC; i += 256)
    rs[i >> 8][i & 255] = region[(size_t)b * NW * NC + i];
  __syncthreads();
  int v = tid >> 3, l8 = tid & 7;
  float sum = 0.f;
  const float* a = rs[w];
  const float* bb = rs[v];
#pragma unroll
  for (int j = 0; j < 32; ++j) sum += a[l8 * 32 + j] * bb[l8 * 32 + j];
  sum += __shfl_xor(sum, 1);
  sum += __shfl_xor(sum, 2);
  sum += __shfl_xor(sum, 4);
  if (l8 == 0) scval[v] = sum * 0.17677669529663687f;  // 32^-0.5
  __syncthreads();
  if (tid == 0) {
    float sc[NW];
#pragma unroll
    for (int j = 0; j < NW; ++j) sc[j] = scval[j];
    for (int kk = 0; kk < NK; ++kk) {
      float best = -__builtin_inff(); int bi = 0;
      for (int j = 0; j < NW; ++j)
        if (sc[j] > best) { best = sc[j]; bi = j; }
      idx[(b * NW + w) * NK + kk] = bi;
      sc[bi] = -__builtin_inff();
    }
  }
}

// K3: MFMA GEMM (natural token order), global_load_lds staging, XOR-swizzled LDS
// (linear dest + pre-swizzled global source + swizzled ds_read).
// qkv[65536][768] = xw @ w_qkv + b_qkv; spike bits (>=2.0) -> q/k/v bitmasks via
// __ballot; per-window flags. 128x128 tile, BK=32 dbuf, 4 waves x 4x4 16x16x32.
__global__ __launch_bounds__(256) void k_gemm(const u16* __restrict__ xw,
                                              const u16* __restrict__ bt,
                                              const float* __restrict__ b_qkv,
                                              u32* __restrict__ qb, u32* __restrict__ kb,
                                              u32* __restrict__ vb,
                                              u32* __restrict__ winflag) {
  __shared__ __align__(16) u16 As[2][128 * 32];
  __shared__ __align__(16) u16 Bs[2][128 * 32];
  __shared__ u32 wfl;

  const int tid = threadIdx.x;
  // XCD-chunked m-major: 6 consecutive v share one m-tile (A panel L2 reuse).
  const int v = (blockIdx.x & 7) * 384 + (blockIdx.x >> 3);
  const int mt = v / 6, nt = v % 6;
  const int m0 = mt * 128, n0 = nt * 128;
  const int wave = tid >> 6, lane = tid & 63;
  const int wr = wave >> 1, wc = wave & 1;

  if (tid == 0) wfl = 0;

  const f32x4 vz = {0.f, 0.f, 0.f, 0.f};
  f32x4 acc[4][4];
#pragma unroll
  for (int m = 0; m < 4; ++m)
#pragma unroll
    for (int n = 0; n < 4; ++n) acc[m][n] = vz;

  auto stage = [&](int buf, int ks) {
    const int k0 = ks * 32;
#pragma unroll
    for (int p = 0; p < 2; ++p) {
      int idx2 = p * 256 + wave * 64 + lane;
      int row = idx2 >> 2, sl = idx2 & 3;
      int ssl = sl ^ ((row >> 1) & 3);          // pre-swizzled source slot
      int lbase = (p * 256 + wave * 64) * 8;    // linear LDS dest (HW adds lane*16B)
      gload16(&xw[(size_t)(m0 + row) * 256 + k0 + ssl * 8], &As[buf][lbase]);
      gload16(&bt[(size_t)(n0 + row) * 256 + k0 + ssl * 8], &Bs[buf][lbase]);
    }
  };

  stage(0, 0);
  __syncthreads();
#pragma unroll
  for (int ks = 0; ks < 8; ++ks) {
    const int buf = ks & 1;
    if (ks < 7) stage(buf ^ 1, ks + 1);
    bf16x8 afr[4], bfr[4];
#pragma unroll
    for (int m = 0; m < 4; ++m) {
      int r = wr * 64 + m * 16 + (lane & 15);
      int phys = (lane >> 4) ^ ((r >> 1) & 3);  // swizzled read
      afr[m] = *reinterpret_cast<const bf16x8*>(&As[buf][r * 32 + phys * 8]);
    }
#pragma unroll
    for (int n = 0; n < 4; ++n) {
      int r = wc * 64 + n * 16 + (lane & 15);
      int phys = (lane >> 4) ^ ((r >> 1) & 3);
      bfr[n] = *reinterpret_cast<const bf16x8*>(&Bs[buf][r * 32 + phys * 8]);
    }
#pragma unroll
    for (int m = 0; m < 4; ++m)
#pragma unroll
      for (int n = 0; n < 4; ++n)
        acc[m][n] = __builtin_amdgcn_mfma_f32_16x16x32_bf16(afr[m], bfr[n], acc[m][n], 0, 0, 0);
    __syncthreads();
  }

  // epilogue: threshold via wave ballot (C/D layout: bit l = row (l>>4)*4+r, col l&15)
  float bias[4];
#pragma unroll
  for (int n = 0; n < 4; ++n) bias[n] = b_qkv[n0 + wc * 64 + n * 16 + (lane & 15)];
  u32* dst = (nt < 2) ? qb : (nt < 4) ? kb : vb;
  const int h0 = (nt * 4) & 7;
  const int g = lane >> 4;
  u32 wfl_loc = 0;
#pragma unroll
  for (int m = 0; m < 4; ++m)
#pragma unroll
    for (int r = 0; r < 4; ++r) {
      u32 words[2];
#pragma unroll
      for (int np = 0; np < 2; ++np) {
        u64 b0 = __ballot(acc[m][2 * np][r] + bias[2 * np] >= 2.0f);
        u64 b1 = __ballot(acc[m][2 * np + 1][r] + bias[2 * np + 1] >= 2.0f);
        words[np] = (u32)((b0 >> (g * 16)) & 0xFFFFu) |
                    ((u32)((b1 >> (g * 16)) & 0xFFFFu) << 16);
      }
      if ((lane & 15) < 2) {
        int np = lane & 1;
        int row = wr * 64 + m * 16 + g * 4 + r;
        u32 wv = words[np];
        dst[(size_t)(m0 + row) * NH + h0 + wc * 2 + np] = wv;
        if (wv) wfl_loc |= 1u << ((row & 31) >> 3);  // ww class
      }
    }
  if (wfl_loc) atomicOr(&wfl, wfl_loc);
  __syncthreads();
  if (tid == 0 && wfl) {
    int t = mt >> 7, b = (mt >> 6) & 1, Lt = (mt >> 3) & 7, hh = mt & 7;
    int w0 = (Lt >> 2) * 16 + (hh >> 1) * 4;
    u32 bit = (nt < 2) ? 1u : (nt < 4) ? 2u : 4u;
    for (int ww = 0; ww < 4; ++ww)
      if (wfl & (1u << ww))
        atomicOr(&winflag[(t * NB + b) * NW + w0 + ww], bit);
  }
}

// K4: attention + proj + window reverse; s-chunked 4x; fast path via window flags.
__global__ __launch_bounds__(256) void k_attn(const u32* __restrict__ qb,
                                              const u32* __restrict__ kb,
                                              const u32* __restrict__ vb,
                                              const int* __restrict__ idx,
                                              const u32* __restrict__ winflag,
                                              const float* __restrict__ w_proj,
                                              const float* __restrict__ b_proj,
                                              float* __restrict__ out) {
  __shared__ u32 qs[64 * NH];
  __shared__ unsigned short kvc[NH * ND * ND];
  __shared__ u32 ksum[NH * ND];
  __shared__ float attnrow[NC];

  int blk = blockIdx.x;  // 1024 = wid*4 + sc
  int wid = blk >> 2, sc = blk & 3;
  int t = wid >> 6, b = (wid >> 5) & 1, w = wid & 31;
  int s0 = sc * 64;
  int tid = threadIdx.x;

  u32 fs = winflag[(t * NB + b) * NW + w];
  int wj[NK];
  u32 fk = 0, fv = 0;
#pragma unroll
  for (int j = 0; j < NK; ++j) {
    wj[j] = idx[(b * NW + w) * NK + j];
    u32 f = winflag[(t * NB + b) * NW + wj[j]];
    fk |= f & 2u; fv |= f & 4u;
  }
  bool skip = !(fs & 1u) || !fk || !fv;

  if (skip) {
    float bp = b_proj[tid];
    for (int s = s0; s < s0 + 64; ++s) out[x_off(t, b, w, s, tid)] = bp;
    return;
  }

  // ---- exact integer slow path (only if spikes exist) ----
  int tb = (t * NB + b) * 8192;
  size_t gb[NK];
#pragma unroll
  for (int j = 0; j < NK; ++j) gb[j] = (size_t)(tb + wofs(wj[j])) * NH;
  size_t qbase = (size_t)(tb + wofs(w)) * NH;
  for (int i = tid; i < 64 * NH; i += 256)
    qs[i] = qb[qbase + (size_t)sofs(s0 + (i >> 3)) * NH + (i & 7)];
  {
    int h = tid >> 5, d = tid & 31;
    u32 cnt = 0;
    for (int n = 0; n < NK * NS; ++n)
      cnt += (kb[gb[n >> 8] + (size_t)sofs(n & 255) * NH + h] >> d) & 1u;
    ksum[tid] = cnt;
  }
  for (int p = tid; p < NH * ND * ND; p += 256) {
    int h = p >> 10, d = (p >> 5) & 31, e = p & 31;
    u32 cnt = 0;
    for (int n = 0; n < NK * NS; ++n) {
      size_t a = gb[n >> 8] + (size_t)sofs(n & 255) * NH + h;
      cnt += ((kb[a] >> d) & (vb[a] >> e)) & 1u;
    }
    kvc[p] = (unsigned short)cnt;
  }
  __syncthreads();
  int h = tid >> 5, e = tid & 31;
  float bpv = b_proj[tid];
  for (int sl = 0; sl < 64; ++sl) {
    u32 qw = qs[sl * NH + h];
    float num = 0.f, den = 0.f;
    for (int d = 0; d < ND; ++d) {
      if ((qw >> d) & 1u) {
        den += (float)ksum[h * ND + d];
        num += (float)kvc[h * ND * ND + d * ND + e];
      }
    }
    attnrow[tid] = num / (den + 1e-6f);
    __syncthreads();
    float acc = bpv;
    for (int c = 0; c < NC; ++c) acc += attnrow[c] * w_proj[c * NC + tid];
    out[x_off(t, b, w, s0 + sl, tid)] = acc;
    __syncthreads();
  }
}

extern "C" void kernel_launch(void* const* d_in, const int* in_sizes, int n_in,
                              void* d_out, int out_size, void* d_ws, size_t ws_size,
                              hipStream_t stream) {
  const float* x      = (const float*)d_in[0];
  const float* w_qkv  = (const float*)d_in[1];
  const float* b_qkv  = (const float*)d_in[2];
  const float* w_proj = (const float*)d_in[3];
  const float* b_proj = (const float*)d_in[4];
  float* out = (float*)d_out;

  char* ws = (char*)d_ws;
  int* idx       = (int*)(ws + 0x200000);         // 1 KB
  u16* bt        = (u16*)(ws + 0x201000);         // 384 KB bf16 [768][256]
  u32* winflag   = (u32*)(ws + 0x270000);         // 1 KB (t,b,w): bit0 q, bit1 k, bit2 v
  float* region  = (float*)(ws + 0x271000);       // 64 KB [b][v][c]
  u32* qb        = (u32*)(ws + 0x300000);         // 2 MB each, natural token order
  u32* kb        = qb + (size_t)NT * NB * NW * NS * NH;
  u32* vb        = kb + (size_t)NT * NB * NW * NS * NH;
  u16* xw        = (u16*)(ws + 0x900000);         // 32 MB bf16 [65536][256]

  hipMemsetAsync(ws + 0x270000, 0, 0x11000, stream);  // winflag + region
  k_prep<<<608, 256, 0, stream>>>(x, w_qkv, xw, bt, region);
  k_scores<<<NB * NW, 256, 0, stream>>>(region, idx);
  k_gemm<<<3072, 256, 0, stream>>>(xw, bt, b_qkv, qb, kb, vb, winflag);
  k_attn<<<NT * NB * NW * 4, 256, 0, stream>>>(qb, kb, vb, idx, winflag, w_proj, b_proj, out);
}

// Round 12
// 86.072 us; speedup vs baseline: 1.5140x; 1.0232x over previous
//
#include <hip/hip_runtime.h>
#include <hip/hip_bf16.h>
#include <stdint.h>

// BiLevelRoutingAttention (spiking LIF), T=4 B=2 L=8x32x32 C=256, fp32 I/O.
#define NT 4
#define NB 2
#define NW 32   // windows = 2*4*4
#define NS 256  // tokens/window = 4*8*8
#define NC 256
#define NH 8
#define ND 32
#define NK 4    // topk

typedef unsigned int u32;
typedef unsigned long long u64;
typedef unsigned short u16;
typedef __attribute__((ext_vector_type(8))) short bf16x8;
typedef __attribute__((ext_vector_type(4))) float f32x4;

// natural token index: tok = (t*NB+b)*8192 + Lt*1024 + Lh*32 + Lw
__device__ __forceinline__ int wofs(int w) {
  return (w >> 4) * 4096 + ((w >> 2) & 3) * 256 + (w & 3) * 8;
}
__device__ __forceinline__ int sofs(int s) {
  return ((s >> 6) << 10) + (((s >> 3) & 7) << 5) + (s & 7);
}
__device__ __forceinline__ size_t x_off(int t, int b, int w, int s, int c) {
  return ((size_t)((t * NB + b) * 8192 + wofs(w) + sofs(s))) * NC + c;
}

// fp32 -> bf16 round-to-nearest-even
__device__ __forceinline__ u32 f2bf(float f) {
  union { float f; u32 i; } u; u.f = f;
  return (u.i + 0x7FFFu + ((u.i >> 16) & 1u)) >> 16;
}

// async global(16B/lane) -> LDS (wave-uniform base + lane*16)
__device__ __forceinline__ void gload16(const u16* g, u16* l) {
  __builtin_amdgcn_global_load_lds(
      (const __attribute__((address_space(1))) void*)g,
      (__attribute__((address_space(3))) void*)l, 16, 0, 0);
}

// K1: prep. Blocks 0..511: x fp32 -> xw bf16 (natural order) + region atomics.
// Blocks 512..607: w_qkv -> bt (transposed bf16).
__global__ __launch_bounds__(256) void k_prep(const float* __restrict__ x,
                                              const float* __restrict__ w_qkv,
                                              u16* __restrict__ xw,
                                              u16* __restrict__ bt,
                                              float* __restrict__ region) {
  int blk = blockIdx.x, tid = threadIdx.x;
  if (blk >= 512) {
    int n = (blk - 512) * 8 + (tid >> 5);  // 0..767
    int kc = tid & 31;                     // k-chunk of 8
    u16 vals[8];
#pragma unroll
    for (int j = 0; j < 8; ++j)
      vals[j] = (u16)f2bf(w_qkv[(size_t)(kc * 8 + j) * 768 + n]);
    *reinterpret_cast<uint4*>(&bt[(size_t)n * 256 + kc * 8]) =
        *reinterpret_cast<const uint4*>(vals);
    return;
  }
  __shared__ float sums[4][4][NC];  // [ww][g][c] 16 KB
  int g = tid >> 6, c4 = tid & 63;
  size_t base = (size_t)blk * 128;  // 128 tokens/block
  float4 s[4];
#pragma unroll
  for (int ww = 0; ww < 4; ++ww) s[ww] = make_float4(0.f, 0.f, 0.f, 0.f);
#pragma unroll
  for (int p = 0; p < 32; ++p) {
    int row = p * 4 + g;
    float4 v = *reinterpret_cast<const float4*>(&x[(base + row) * NC + c4 * 4]);
    uint2 bf;
    bf.x = f2bf(v.x) | (f2bf(v.y) << 16);
    bf.y = f2bf(v.z) | (f2bf(v.w) << 16);
    *reinterpret_cast<uint2*>(&xw[(base + row) * NC + c4 * 4]) = bf;
    int ww = (p & 7) >> 1;  // = (row&31)>>3
    s[ww].x += v.x; s[ww].y += v.y; s[ww].z += v.z; s[ww].w += v.w;
  }
#pragma unroll
  for (int ww = 0; ww < 4; ++ww)
    *reinterpret_cast<float4*>(&sums[ww][g][c4 * 4]) = s[ww];
  __syncthreads();
  // blk = tb*64 + Lt*8 + hp ; wh = hp>>1, wt = Lt>>2
  int b = (blk >> 6) & 1;
  int wt = ((blk >> 3) & 7) >> 2, wh = (blk & 7) >> 1;
  int v0 = wt * 16 + wh * 4;
  int c = tid;
#pragma unroll
  for (int ww = 0; ww < 4; ++ww) {
    float tot = (sums[ww][0][c] + sums[ww][1][c] + sums[ww][2][c] + sums[ww][3][c]) *
                (1.0f / 1024.0f);
    atomicAdd(&region[((size_t)b * NW + v0 + ww) * NC + c], tot);
  }
}

// K2: scores + top-4 (ties -> lower index, matching jax.lax.top_k)
__global__ __launch_bounds__(256) void k_scores(const float* __restrict__ region,
                                                int* __restrict__ idx) {
  __shared__ float rs[NW][NC];  // 32 KB
  __shared__ float scval[NW];
  int blk = blockIdx.x;  // 64 = b*32 + w
  int b = blk >> 5, w = blk & 31;
  int tid = threadIdx.x;
  for (int i = tid; i < NW * NC; i += 256)
    rs[i >> 8][i & 255] = region[(size_t)b * NW * NC + i];
  __syncthreads();
  int v = tid >> 3, l8 = tid & 7;
  float sum = 0.f;
  const float* a = rs[w];
  const float* bb = rs[v];
#pragma unroll
  for (int j = 0; j < 32; ++j) sum += a[l8 * 32 + j] * bb[l8 * 32 + j];
  sum += __shfl_xor(sum, 1);
  sum += __shfl_xor(sum, 2);
  sum += __shfl_xor(sum, 4);
  if (l8 == 0) scval[v] = sum * 0.17677669529663687f;  // 32^-0.5
  __syncthreads();
  if (tid == 0) {
    float sc[NW];
#pragma unroll
    for (int j = 0; j < NW; ++j) sc[j] = scval[j];
    for (int kk = 0; kk < NK; ++kk) {
      float best = -__builtin_inff(); int bi = 0;
      for (int j = 0; j < NW; ++j)
        if (sc[j] > best) { best = sc[j]; bi = j; }
      idx[(b * NW + w) * NK + kk] = bi;
      sc[bi] = -__builtin_inff();
    }
  }
}

// K3: MFMA GEMM, 128x256 tile (nt = q/k/v), BK=32 dbuf, 4 waves x 4x8 16x16x32.
// global_load_lds staging, XOR-swizzled LDS (linear dest + pre-swizzled source +
// swizzled ds_read). Spike bits (>=2.0) -> bitmasks via __ballot + window flags.
__global__ __launch_bounds__(256, 2) void k_gemm(const u16* __restrict__ xw,
                                                 const u16* __restrict__ bt,
                                                 const float* __restrict__ b_qkv,
                                                 u32* __restrict__ qb, u32* __restrict__ kb,
                                                 u32* __restrict__ vb,
                                                 u32* __restrict__ winflag) {
  __shared__ __align__(16) u16 As[2][128 * 32];  // 16 KB
  __shared__ __align__(16) u16 Bs[2][256 * 32];  // 32 KB
  __shared__ u32 wfl;

  const int tid = threadIdx.x;
  // XCD-chunked m-major: 3 consecutive v (q,k,v) share one m-tile (A L2 reuse).
  const int v = (blockIdx.x & 7) * 192 + (blockIdx.x >> 3);
  const int mt = v / 3, nt = v % 3;
  const int m0 = mt * 128, n0 = nt * 256;
  const int wave = tid >> 6, lane = tid & 63;
  const int wr = wave >> 1, wc = wave & 1;  // 2x2 waves of 64x128

  if (tid == 0) wfl = 0;

  const f32x4 vz = {0.f, 0.f, 0.f, 0.f};
  f32x4 acc[4][8];
#pragma unroll
  for (int m = 0; m < 4; ++m)
#pragma unroll
    for (int n = 0; n < 8; ++n) acc[m][n] = vz;

  auto stage = [&](int buf, int ks) {
    const int k0 = ks * 32;
    // A: 512 16B-chunks (128 rows x 4 slots), 2 wave-rounds
#pragma unroll
    for (int p = 0; p < 2; ++p) {
      int cbase = (wave * 2 + p) * 64;
      int c = cbase + lane;
      int row = c >> 2, sl = c & 3;
      int ssl = sl ^ ((row >> 1) & 3);
      gload16(&xw[(size_t)(m0 + row) * 256 + k0 + ssl * 8], &As[buf][cbase * 8]);
    }
    // B: 1024 16B-chunks (256 rows x 4 slots), 4 wave-rounds
#pragma unroll
    for (int p = 0; p < 4; ++p) {
      int cbase = (wave * 4 + p) * 64;
      int c = cbase + lane;
      int row = c >> 2, sl = c & 3;
      int ssl = sl ^ ((row >> 1) & 3);
      gload16(&bt[(size_t)(n0 + row) * 256 + k0 + ssl * 8], &Bs[buf][cbase * 8]);
    }
  };

  stage(0, 0);
  __syncthreads();
#pragma unroll
  for (int ks = 0; ks < 8; ++ks) {
    const int buf = ks & 1;
    if (ks < 7) stage(buf ^ 1, ks + 1);
    bf16x8 afr[4], bfr[8];
#pragma unroll
    for (int m = 0; m < 4; ++m) {
      int r = wr * 64 + m * 16 + (lane & 15);
      int phys = (lane >> 4) ^ ((r >> 1) & 3);
      afr[m] = *reinterpret_cast<const bf16x8*>(&As[buf][r * 32 + phys * 8]);
    }
#pragma unroll
    for (int n = 0; n < 8; ++n) {
      int r = wc * 128 + n * 16 + (lane & 15);
      int phys = (lane >> 4) ^ ((r >> 1) & 3);
      bfr[n] = *reinterpret_cast<const bf16x8*>(&Bs[buf][r * 32 + phys * 8]);
    }
#pragma unroll
    for (int m = 0; m < 4; ++m)
#pragma unroll
      for (int n = 0; n < 8; ++n)
        acc[m][n] = __builtin_amdgcn_mfma_f32_16x16x32_bf16(afr[m], bfr[n], acc[m][n], 0, 0, 0);
    __syncthreads();
  }

  // epilogue: threshold via wave ballot (C/D: bit l -> row (l>>4)*4+r, col l&15)
  float bias[8];
#pragma unroll
  for (int n = 0; n < 8; ++n) bias[n] = b_qkv[n0 + wc * 128 + n * 16 + (lane & 15)];
  u32* dst = (nt == 0) ? qb : (nt == 1) ? kb : vb;
  const int g = lane >> 4;
  u32 wfl_loc = 0;
#pragma unroll
  for (int m = 0; m < 4; ++m)
#pragma unroll
    for (int r = 0; r < 4; ++r) {
      u32 words[4];
#pragma unroll
      for (int jp = 0; jp < 4; ++jp) {
        u64 b0 = __ballot(acc[m][2 * jp][r] + bias[2 * jp] >= 2.0f);
        u64 b1 = __ballot(acc[m][2 * jp + 1][r] + bias[2 * jp + 1] >= 2.0f);
        words[jp] = (u32)((b0 >> (g * 16)) & 0xFFFFu) |
                    ((u32)((b1 >> (g * 16)) & 0xFFFFu) << 16);
      }
      if ((lane & 15) < 4) {
        int jp = lane & 3;
        int row = wr * 64 + m * 16 + g * 4 + r;
        u32 wv = words[jp];
        dst[(size_t)(m0 + row) * NH + wc * 4 + jp] = wv;  // head = wc*4+jp
        if (wv) wfl_loc |= 1u << ((row & 31) >> 3);       // ww class
      }
    }
  if (wfl_loc) atomicOr(&wfl, wfl_loc);
  __syncthreads();
  if (tid == 0 && wfl) {
    int t = mt >> 7, b = (mt >> 6) & 1, Lt = (mt >> 3) & 7, hh = mt & 7;
    int w0 = (Lt >> 2) * 16 + (hh >> 1) * 4;
    u32 bit = 1u << nt;
    for (int ww = 0; ww < 4; ++ww)
      if (wfl & (1u << ww))
        atomicOr(&winflag[(t * NB + b) * NW + w0 + ww], bit);
  }
}

// K4: attention + proj + window reverse; s-chunked 4x; fast path via window flags.
__global__ __launch_bounds__(256) void k_attn(const u32* __restrict__ qb,
                                              const u32* __restrict__ kb,
                                              const u32* __restrict__ vb,
                                              const int* __restrict__ idx,
                                              const u32* __restrict__ winflag,
                                              const float* __restrict__ w_proj,
                                              const float* __restrict__ b_proj,
                                              float* __restrict__ out) {
  __shared__ u32 qs[64 * NH];
  __shared__ unsigned short kvc[NH * ND * ND];
  __shared__ u32 ksum[NH * ND];
  __shared__ float attnrow[NC];

  int blk = blockIdx.x;  // 1024 = wid*4 + sc
  int wid = blk >> 2, sc = blk & 3;
  int t = wid >> 6, b = (wid >> 5) & 1, w = wid & 31;
  int s0 = sc * 64;
  int tid = threadIdx.x;

  u32 fs = winflag[(t * NB + b) * NW + w];
  int wj[NK];
  u32 fk = 0, fv = 0;
#pragma unroll
  for (int j = 0; j < NK; ++j) {
    wj[j] = idx[(b * NW + w) * NK + j];
    u32 f = winflag[(t * NB + b) * NW + wj[j]];
    fk |= f & 2u; fv |= f & 4u;
  }
  bool skip = !(fs & 1u) || !fk || !fv;

  if (skip) {
    float bp = b_proj[tid];
    for (int s = s0; s < s0 + 64; ++s) out[x_off(t, b, w, s, tid)] = bp;
    return;
  }

  // ---- exact integer slow path (only if spikes exist) ----
  int tb = (t * NB + b) * 8192;
  size_t gb[NK];
#pragma unroll
  for (int j = 0; j < NK; ++j) gb[j] = (size_t)(tb + wofs(wj[j])) * NH;
  size_t qbase = (size_t)(tb + wofs(w)) * NH;
  for (int i = tid; i < 64 * NH; i += 256)
    qs[i] = qb[qbase + (size_t)sofs(s0 + (i >> 3)) * NH + (i & 7)];
  {
    int h = tid >> 5, d = tid & 31;
    u32 cnt = 0;
    for (int n = 0; n < NK * NS; ++n)
      cnt += (kb[gb[n >> 8] + (size_t)sofs(n & 255) * NH + h] >> d) & 1u;
    ksum[tid] = cnt;
  }
  for (int p = tid; p < NH * ND * ND; p += 256) {
    int h = p >> 10, d = (p >> 5) & 31, e = p & 31;
    u32 cnt = 0;
    for (int n = 0; n < NK * NS; ++n) {
      size_t a = gb[n >> 8] + (size_t)sofs(n & 255) * NH + h;
      cnt += ((kb[a] >> d) & (vb[a] >> e)) & 1u;
    }
    kvc[p] = (unsigned short)cnt;
  }
  __syncthreads();
  int h = tid >> 5, e = tid & 31;
  float bpv = b_proj[tid];
  for (int sl = 0; sl < 64; ++sl) {
    u32 qw = qs[sl * NH + h];
    float num = 0.f, den = 0.f;
    for (int d = 0; d < ND; ++d) {
      if ((qw >> d) & 1u) {
        den += (float)ksum[h * ND + d];
        num += (float)kvc[h * ND * ND + d * ND + e];
      }
    }
    attnrow[tid] = num / (den + 1e-6f);
    __syncthreads();
    float acc = bpv;
    for (int c = 0; c < NC; ++c) acc += attnrow[c] * w_proj[c * NC + tid];
    out[x_off(t, b, w, s0 + sl, tid)] = acc;
    __syncthreads();
  }
}

extern "C" void kernel_launch(void* const* d_in, const int* in_sizes, int n_in,
                              void* d_out, int out_size, void* d_ws, size_t ws_size,
                              hipStream_t stream) {
  const float* x      = (const float*)d_in[0];
  const float* w_qkv  = (const float*)d_in[1];
  const float* b_qkv  = (const float*)d_in[2];
  const float* w_proj = (const float*)d_in[3];
  const float* b_proj = (const float*)d_in[4];
  float* out = (float*)d_out;

  char* ws = (char*)d_ws;
  int* idx       = (int*)(ws + 0x200000);         // 1 KB
  u16* bt        = (u16*)(ws + 0x201000);         // 384 KB bf16 [768][256]
  u32* winflag   = (u32*)(ws + 0x270000);         // 1 KB (t,b,w): bit0 q, bit1 k, bit2 v
  float* region  = (float*)(ws + 0x271000);       // 64 KB [b][v][c]
  u32* qb        = (u32*)(ws + 0x300000);         // 2 MB each, natural token order
  u32* kb        = qb + (size_t)NT * NB * NW * NS * NH;
  u32* vb        = kb + (size_t)NT * NB * NW * NS * NH;
  u16* xw        = (u16*)(ws + 0x900000);         // 32 MB bf16 [65536][256]

  hipMemsetAsync(ws + 0x270000, 0, 0x11000, stream);  // winflag + region
  k_prep<<<608, 256, 0, stream>>>(x, w_qkv, xw, bt, region);
  k_scores<<<NB * NW, 256, 0, stream>>>(region, idx);
  k_gemm<<<1536, 256, 0, stream>>>(xw, bt, b_qkv, qb, kb, vb, winflag);
  k_attn<<<NT * NB * NW * 4, 256, 0, stream>>>(qb, kb, vb, idx, winflag, w_proj, b_proj, out);
}